// Round 9
// baseline (85.535 us; speedup 1.0000x reference)
//
#include <hip/hip_runtime.h>
#include <math.h>

#define NPIX 784
#define NCLS 10
#define ROWS 8            // rows per block = 4 waves x 2 rows each
#define BLOCK 256

// Circuit identity: all RY gates (no entanglers) compose additively per wire:
// <Z_w> = cos(x_w + sum_l theta[l][w]).  feats[f], f = patch*4 + w.
// A float4 of x at (image row i, col j0=4*j4) covers wires (wb,wb+1) of
// patches P and P+1, wb=(i&1)*2, P=(i>>1)*14+j4*2.
// Key change vs R8: ALL x loads for the wave's 2 batch rows are issued
// back-to-back into registers before any compute (8 float4/lane in flight)
// to cover HBM latency; W is read from LDS as 2x ds_read_b64 per class.
__global__ __launch_bounds__(256)
void quanv_fused_kernel(const float* __restrict__ x,
                        const float* __restrict__ theta,
                        const float* __restrict__ W,
                        const float* __restrict__ bias,
                        float* __restrict__ out) {
    __shared__ float Wl[NCLS * NPIX];   // 30.6 KB, original f-layout
    int tid = threadIdx.x;

    // ---- stage W: pure vectorized copy (1960 float4) ----
    const float4* W4 = reinterpret_cast<const float4*>(W);
    float4* Wl4 = reinterpret_cast<float4*>(Wl);
#pragma unroll
    for (int i = 0; i < 8; ++i) {
        int idx = tid + (i << 8);
        if (idx < (NCLS * NPIX) / 4) Wl4[idx] = W4[idx];
    }

    float t0 = theta[0] + theta[4] + theta[8];
    float t1 = theta[1] + theta[5] + theta[9];
    float t2 = theta[2] + theta[6] + theta[10];
    float t3 = theta[3] + theta[7] + theta[11];
    __syncthreads();

    int tx = tid & 63;                      // lane in wave
    int wv = tid >> 6;                      // wave 0..3
    int row0 = blockIdx.x * ROWS + wv * 2;
    const float4* xr0 = reinterpret_cast<const float4*>(x + (size_t)row0 * NPIX);
    const float4* xr1 = xr0 + (NPIX / 4);

    // ---- hoist all x loads: 196 float4/row = 3*64 + 4 ----
    bool tail = (tx < 4);
    int c3 = tail ? (tx + 192) : 0;         // clamp inactive lanes in-bounds
    float4 xa0 = xr0[tx];
    float4 xa1 = xr0[tx + 64];
    float4 xa2 = xr0[tx + 128];
    float4 xa3 = xr0[c3];
    float4 xb0 = xr1[tx];
    float4 xb1 = xr1[tx + 64];
    float4 xb2 = xr1[tx + 128];
    float4 xb3 = xr1[c3];

    float acc0[NCLS], acc1[NCLS];
#pragma unroll
    for (int k = 0; k < NCLS; ++k) { acc0[k] = 0.f; acc1[k] = 0.f; }

    // process one float4-chunk c (covers 2 patches' wire pair) for 2 rows
    auto do_chunk = [&](int c, const float4& va, const float4& vb) {
        unsigned ci = (unsigned)c;
        int i  = ci / 7;                    // image row (magic-mul)
        int j4 = ci - i * 7;
        int wb = (i & 1) << 1;
        int P  = (i >> 1) * 14 + j4 * 2;
        int base = (P << 2) + wb;           // float index in class-0 row
        float tA = (i & 1) ? t2 : t0;
        float tB = (i & 1) ? t3 : t1;
        float fa0 = __cosf(va.x + tA), fa1 = __cosf(va.y + tB);
        float fa2 = __cosf(va.z + tA), fa3 = __cosf(va.w + tB);
        float fb0 = __cosf(vb.x + tA), fb1 = __cosf(vb.y + tB);
        float fb2 = __cosf(vb.z + tA), fb3 = __cosf(vb.w + tB);
#pragma unroll
        for (int k = 0; k < NCLS; ++k) {
            float2 w0 = *reinterpret_cast<const float2*>(&Wl[k * NPIX + base]);
            float2 w1 = *reinterpret_cast<const float2*>(&Wl[k * NPIX + base + 4]);
            acc0[k] += fa0 * w0.x + fa1 * w0.y + fa2 * w1.x + fa3 * w1.y;
            acc1[k] += fb0 * w0.x + fb1 * w0.y + fb2 * w1.x + fb3 * w1.y;
        }
    };

    do_chunk(tx,       xa0, xb0);
    do_chunk(tx + 64,  xa1, xb1);
    do_chunk(tx + 128, xa2, xb2);
    if (tail) do_chunk(tx + 192, xa3, xb3);

    // ---- full-wave (64-lane) reduction ----
#pragma unroll
    for (int k = 0; k < NCLS; ++k) {
        float v0 = acc0[k], v1 = acc1[k];
        v0 += __shfl_xor(v0, 1);  v1 += __shfl_xor(v1, 1);
        v0 += __shfl_xor(v0, 2);  v1 += __shfl_xor(v1, 2);
        v0 += __shfl_xor(v0, 4);  v1 += __shfl_xor(v1, 4);
        v0 += __shfl_xor(v0, 8);  v1 += __shfl_xor(v1, 8);
        v0 += __shfl_xor(v0, 16); v1 += __shfl_xor(v1, 16);
        v0 += __shfl_xor(v0, 32); v1 += __shfl_xor(v1, 32);
        acc0[k] = v0; acc1[k] = v1;
    }

    if (tx == 0 || tx == 32) {
        const float* a = (tx == 0) ? acc0 : acc1;
        int row = (tx == 0) ? row0 : row0 + 1;
        float logits[NCLS];
        float m = -1e30f;
#pragma unroll
        for (int k = 0; k < NCLS; ++k) {
            logits[k] = a[k] + bias[k];
            m = fmaxf(m, logits[k]);
        }
        float sum = 0.f;
#pragma unroll
        for (int k = 0; k < NCLS; ++k) sum += expf(logits[k] - m);
        float lse = m + logf(sum);
#pragma unroll
        for (int k = 0; k < NCLS; ++k) out[row * NCLS + k] = logits[k] - lse;
    }
}

extern "C" void kernel_launch(void* const* d_in, const int* in_sizes, int n_in,
                              void* d_out, int out_size, void* d_ws, size_t ws_size,
                              hipStream_t stream) {
    const float* x     = (const float*)d_in[0];
    const float* theta = (const float*)d_in[1];
    const float* W     = (const float*)d_in[2];
    const float* bias  = (const float*)d_in[3];
    float* out = (float*)d_out;

    int B = in_sizes[0] / NPIX;          // 8192
    int grid = B / ROWS;                 // 1024 blocks -> 4 blocks/CU
    quanv_fused_kernel<<<grid, BLOCK, 0, stream>>>(x, theta, W, bias, out);
}

// Round 11
// 79.913 us; speedup vs baseline: 1.0704x; 1.0704x over previous
//
#include <hip/hip_runtime.h>
#include <math.h>

#define NPIX 784
#define NCLS 10
#define ROWS 16           // rows per block (8 lane-groups x 2 rows)
#define BLOCK 256

// Circuit identity: all gates are RY (no entanglers); RY on one wire compose
// additively, so <Z_w> = cos(x_w + sum_l theta[l][w]).
// feats[f], f = patch*4 + w; wire w reads pixel (2pr + (w>>1), 2pc + (w&1)).
// W stays in original f-layout in LDS (straight float4 copy, no permute);
// x is read in patch order (two float2 loads per patch per row).
// NOTE: this is the best-measured variant (79.1 us); resubmitted verbatim as
// an A/A noise calibration — R8 (occupancy 2x) and R9 (MLP hoist) both
// regressed, implying kernel time ~5us vs ~74us harness floor.
__global__ __launch_bounds__(256)
void quanv_fused_kernel(const float* __restrict__ x,
                        const float* __restrict__ theta,
                        const float* __restrict__ W,
                        const float* __restrict__ bias,
                        float* __restrict__ out) {
    __shared__ float Wl[NCLS * NPIX];   // 30.6 KB, original layout
    int tid = threadIdx.x;

    // ---- stage W: pure vectorized copy ----
    const float4* W4 = reinterpret_cast<const float4*>(W);
    float4* Wl4 = reinterpret_cast<float4*>(Wl);
    for (int i = tid; i < (NCLS * NPIX) / 4; i += BLOCK) Wl4[i] = W4[i];

    // per-wire angle offsets (L1-cached scalar reads)
    float t0 = theta[0] + theta[4] + theta[8];
    float t1 = theta[1] + theta[5] + theta[9];
    float t2 = theta[2] + theta[6] + theta[10];
    float t3 = theta[3] + theta[7] + theta[11];
    __syncthreads();

    int tx = tid & 31;
    int g  = tid >> 5;                      // 0..7
    int row0 = blockIdx.x * ROWS + g * 2;
    const float* xr0 = x + (size_t)row0 * NPIX;
    const float* xr1 = xr0 + NPIX;

    float acc0[NCLS], acc1[NCLS];
#pragma unroll
    for (int k = 0; k < NCLS; ++k) { acc0[k] = 0.f; acc1[k] = 0.f; }

#pragma unroll
    for (int s = 0; s < 7; ++s) {           // 196 patches: 6 full + 4-lane tail
        int p = tx + (s << 5);
        bool active = (s < 6) | (tx < 4);
        if (active) {
            int pr = p / 14;
            int pc = p - pr * 14;
            int off0 = pr * 56 + pc * 2;    // pixel idx of (2pr, 2pc)
            int off1 = off0 + 28;           // row 2pr+1
            float2 a0 = *reinterpret_cast<const float2*>(xr0 + off0);
            float2 b0 = *reinterpret_cast<const float2*>(xr0 + off1);
            float2 a1 = *reinterpret_cast<const float2*>(xr1 + off0);
            float2 b1 = *reinterpret_cast<const float2*>(xr1 + off1);
            float f00 = __cosf(a0.x + t0), f01 = __cosf(a0.y + t1);
            float f02 = __cosf(b0.x + t2), f03 = __cosf(b0.y + t3);
            float f10 = __cosf(a1.x + t0), f11 = __cosf(a1.y + t1);
            float f12 = __cosf(b1.x + t2), f13 = __cosf(b1.y + t3);
#pragma unroll
            for (int k = 0; k < NCLS; ++k) {
                float4 wv = *reinterpret_cast<const float4*>(&Wl[k * NPIX + (p << 2)]);
                acc0[k] += f00 * wv.x + f01 * wv.y + f02 * wv.z + f03 * wv.w;
                acc1[k] += f10 * wv.x + f11 * wv.y + f12 * wv.z + f13 * wv.w;
            }
        }
    }

    // ---- 32-lane reduction (xor stays inside each row's lane group) ----
#pragma unroll
    for (int k = 0; k < NCLS; ++k) {
        float v0 = acc0[k], v1 = acc1[k];
        v0 += __shfl_xor(v0, 1);  v1 += __shfl_xor(v1, 1);
        v0 += __shfl_xor(v0, 2);  v1 += __shfl_xor(v1, 2);
        v0 += __shfl_xor(v0, 4);  v1 += __shfl_xor(v1, 4);
        v0 += __shfl_xor(v0, 8);  v1 += __shfl_xor(v1, 8);
        v0 += __shfl_xor(v0, 16); v1 += __shfl_xor(v1, 16);
        acc0[k] = v0; acc1[k] = v1;
    }

    // lane 0 -> row0, lane 16 -> row1 (both hold the full sums)
    if (tx == 0 || tx == 16) {
        const float* a = (tx == 0) ? acc0 : acc1;
        int row = (tx == 0) ? row0 : row0 + 1;
        float logits[NCLS];
        float m = -1e30f;
#pragma unroll
        for (int k = 0; k < NCLS; ++k) {
            logits[k] = a[k] + bias[k];
            m = fmaxf(m, logits[k]);
        }
        float sum = 0.f;
#pragma unroll
        for (int k = 0; k < NCLS; ++k) sum += expf(logits[k] - m);
        float lse = m + logf(sum);
#pragma unroll
        for (int k = 0; k < NCLS; ++k) out[row * NCLS + k] = logits[k] - lse;
    }
}

extern "C" void kernel_launch(void* const* d_in, const int* in_sizes, int n_in,
                              void* d_out, int out_size, void* d_ws, size_t ws_size,
                              hipStream_t stream) {
    const float* x     = (const float*)d_in[0];
    const float* theta = (const float*)d_in[1];
    const float* W     = (const float*)d_in[2];
    const float* bias  = (const float*)d_in[3];
    float* out = (float*)d_out;

    int B = in_sizes[0] / NPIX;          // 8192
    int grid = B / ROWS;                 // 512 blocks
    quanv_fused_kernel<<<grid, BLOCK, 0, stream>>>(x, theta, W, bias, out);
}